// Round 5
// baseline (1638.962 us; speedup 1.0000x reference)
//
#include <hip/hip_runtime.h>
#include <hip/hip_bf16.h>

typedef __hip_bfloat16 bf16;

#define C_IN  512
#define N_SP  1024
#define R_ALL 640   // rows 0..63 = q, 64..127 = k, 128..639 = v
#define BATCH 32

// Mixed-dtype accessors: f32 flag selects fp32 or bf16 view of the SAME buffer.
__device__ __forceinline__ float ldmix(const void* p, size_t i, int f32) {
    return f32 ? ((const float*)p)[i] : __bfloat162float(((const bf16*)p)[i]);
}
__device__ __forceinline__ void stmix(void* p, size_t i, float v, int f32) {
    if (f32) ((float*)p)[i] = v;
    else     ((bf16*)p)[i] = __float2bfloat16(v);
}

// ---------------------------------------------------------------------------
// K0: dtype detector — FIXED to sample EVEN halfwords.
// Little-endian fp32: even halfword = LOW mantissa bits (uniform garbage,
// ~25% plausible bf16 exponents); bf16 array: even halfword = a real bf16
// value (~100% plausible). Writes flag: 1 = fp32, 0 = bf16.
// ---------------------------------------------------------------------------
__global__ void k_detect(const unsigned short* __restrict__ xh, int* __restrict__ flag)
{
    __shared__ int red[256];
    int tid = threadIdx.x;
    unsigned short h = xh[2 * tid];              // EVEN halfwords 0,2,...,510
    int e = (h >> 7) & 0xFF;
    int plaus = (e == 0 || (e >= 96 && e <= 159)) ? 1 : 0;
    red[tid] = plaus;
    __syncthreads();
    for (int s = 128; s > 0; s >>= 1) { if (tid < s) red[tid] += red[tid + s]; __syncthreads(); }
    if (tid == 0) *flag = (red[0] < 192) ? 1 : 0;
}

// ---------------------------------------------------------------------------
// K1: spectral norm — computes ONLY 1/sigma per matrix.
// sigma = || W v || with v = normalize(W^T u)  (algebraically equal to ref).
// ---------------------------------------------------------------------------
__global__ __launch_bounds__(512) void k_spectral(
    const void* __restrict__ Wq, const void* __restrict__ uq,
    const void* __restrict__ Wk, const void* __restrict__ uk,
    const void* __restrict__ Wv, const void* __restrict__ uv,
    const int* __restrict__ flag, float* __restrict__ sig)
{
    __shared__ float sh_u[512];
    __shared__ float sh_v[512];
    __shared__ float sh_red[512];
    int f32 = *flag;
    const void *W, *u; int out;
    if (blockIdx.x == 0)      { W = Wq; u = uq; out = 64;  }
    else if (blockIdx.x == 1) { W = Wk; u = uk; out = 64;  }
    else                      { W = Wv; u = uv; out = 512; }
    int tid = threadIdx.x;
    if (tid < out) sh_u[tid] = ldmix(u, tid, f32);
    __syncthreads();

    float vacc = 0.f;
    for (int o = 0; o < out; ++o)
        vacc += ldmix(W, (size_t)o * C_IN + tid, f32) * sh_u[o];
    sh_red[tid] = vacc * vacc;
    __syncthreads();
    for (int s = 256; s > 0; s >>= 1) { if (tid < s) sh_red[tid] += sh_red[tid + s]; __syncthreads(); }
    float vinv = 1.f / sqrtf(sh_red[0]);
    __syncthreads();
    sh_v[tid] = vacc * vinv;
    __syncthreads();

    float t = 0.f;
    if (tid < out) {
        for (int c = 0; c < C_IN; ++c)
            t += ldmix(W, (size_t)tid * C_IN + c, f32) * sh_v[c];
    }
    sh_red[tid] = (tid < out) ? t * t : 0.f;
    __syncthreads();
    for (int s = 256; s > 0; s >>= 1) { if (tid < s) sh_red[tid] += sh_red[tid + s]; __syncthreads(); }
    if (tid == 0) sig[blockIdx.x] = 1.f / sqrtf(sh_red[0]);
}

// ---------------------------------------------------------------------------
// K2: QKV projection for one batch-group, weights scaled on the fly.
// Y[bl][r][n] = (1/sigma) * sum_c W[r][c] * x[batch0+bl][c][n] + b[r]
// blockIdx.y: 0 -> q rows, 1 -> k rows, 2..9 -> v rows.
// ---------------------------------------------------------------------------
__global__ __launch_bounds__(256) void k_qkv(
    const void* __restrict__ Wq, const void* __restrict__ bq,
    const void* __restrict__ Wk, const void* __restrict__ bk,
    const void* __restrict__ Wv, const void* __restrict__ bv,
    const float* __restrict__ sig, const int* __restrict__ flag,
    const void* __restrict__ x, bf16* __restrict__ Y, int batch0)
{
    __shared__ float As[16][64 + 4];    // [k][r]
    __shared__ float Bs[16][128 + 4];   // [k][n]
    int f32 = *flag;
    int bl = blockIdx.z;
    int r0 = blockIdx.y * 64;
    int n0 = blockIdx.x * 128;
    const void *Wt, *bt; float sc; int rbase;
    if (blockIdx.y == 0)      { Wt = Wq; bt = bq; sc = sig[0]; rbase = 0; }
    else if (blockIdx.y == 1) { Wt = Wk; bt = bk; sc = sig[1]; rbase = 0; }
    else                      { Wt = Wv; bt = bv; sc = sig[2]; rbase = (blockIdx.y - 2) * 64; }
    int tid = threadIdx.x, tx = tid & 15, ty = tid >> 4;
    const size_t xoff = (size_t)(batch0 + bl) * C_IN * N_SP;
    bf16* Yb = Y + (size_t)bl * R_ALL * N_SP;
    float acc[4][8];
#pragma unroll
    for (int i = 0; i < 4; ++i)
#pragma unroll
        for (int j = 0; j < 8; ++j) acc[i][j] = 0.f;

    for (int k0 = 0; k0 < C_IN; k0 += 16) {
#pragma unroll
        for (int i = 0; i < 4; ++i) {
            int idx = tid + i * 256; int r = idx >> 4; int kk = idx & 15;
            As[kk][r] = ldmix(Wt, (size_t)(rbase + r) * C_IN + k0 + kk, f32) * sc;
        }
#pragma unroll
        for (int i = 0; i < 8; ++i) {
            int idx = tid + i * 256; int kk = idx >> 7; int nn = idx & 127;
            Bs[kk][nn] = ldmix(x, xoff + (size_t)(k0 + kk) * N_SP + n0 + nn, f32);
        }
        __syncthreads();
#pragma unroll
        for (int kk = 0; kk < 16; ++kk) {
            float av[4], bv8[8];
#pragma unroll
            for (int i = 0; i < 4; ++i) av[i] = As[kk][ty * 4 + i];
#pragma unroll
            for (int j = 0; j < 8; ++j) bv8[j] = Bs[kk][tx * 8 + j];
#pragma unroll
            for (int i = 0; i < 4; ++i)
#pragma unroll
                for (int j = 0; j < 8; ++j) acc[i][j] = fmaf(av[i], bv8[j], acc[i][j]);
        }
        __syncthreads();
    }
#pragma unroll
    for (int i = 0; i < 4; ++i) {
        int rl = ty * 4 + i;
        float bi = ldmix(bt, rbase + rl, f32);
#pragma unroll
        for (int j = 0; j < 8; ++j)
            Yb[(size_t)(r0 + rl) * N_SP + n0 + tx * 8 + j] = __float2bfloat16(acc[i][j] + bi);
    }
}

// ---------------------------------------------------------------------------
// K3: scores.  S[bl][m][n] = sum_{o<64} Yk[o][m] * Yq[o][n]   (S[m,n]=qk[n,m])
// ---------------------------------------------------------------------------
__global__ __launch_bounds__(256) void k_qk(const bf16* __restrict__ Y, bf16* __restrict__ S)
{
    __shared__ float As[16][132];   // [o][m]
    __shared__ float Bs[16][132];   // [o][n]
    int bl = blockIdx.z, m0 = blockIdx.y * 128, n0 = blockIdx.x * 128;
    int tid = threadIdx.x, tx = tid & 15, ty = tid >> 4;
    const bf16* Yb = Y + (size_t)bl * R_ALL * N_SP;
    float acc[8][8];
#pragma unroll
    for (int i = 0; i < 8; ++i)
#pragma unroll
        for (int j = 0; j < 8; ++j) acc[i][j] = 0.f;

    for (int k0 = 0; k0 < 64; k0 += 16) {
#pragma unroll
        for (int i = 0; i < 8; ++i) {
            int idx = tid + i * 256; int o = idx >> 7; int mm = idx & 127;
            As[o][mm] = __bfloat162float(Yb[(size_t)(64 + k0 + o) * N_SP + m0 + mm]);
            Bs[o][mm] = __bfloat162float(Yb[(size_t)(k0 + o) * N_SP + n0 + mm]);
        }
        __syncthreads();
#pragma unroll
        for (int o = 0; o < 16; ++o) {
            float av[8], bv8[8];
#pragma unroll
            for (int i = 0; i < 8; ++i) av[i] = As[o][ty * 8 + i];
#pragma unroll
            for (int j = 0; j < 8; ++j) bv8[j] = Bs[o][tx * 8 + j];
#pragma unroll
            for (int i = 0; i < 8; ++i)
#pragma unroll
                for (int j = 0; j < 8; ++j) acc[i][j] = fmaf(av[i], bv8[j], acc[i][j]);
        }
        __syncthreads();
    }
    bf16* Sb = S + (size_t)bl * N_SP * N_SP;
#pragma unroll
    for (int i = 0; i < 8; ++i)
#pragma unroll
        for (int j = 0; j < 8; ++j)
            Sb[(size_t)(m0 + ty * 8 + i) * N_SP + n0 + tx * 8 + j] = __float2bfloat16(acc[i][j]);
}

// ---------------------------------------------------------------------------
// K4: row softmax of S (over n), in place.  Exponent clamped (NaN-eating).
// ---------------------------------------------------------------------------
__global__ __launch_bounds__(256) void k_softmax(bf16* __restrict__ S)
{
    __shared__ float red[256];
    bf16* p = S + (size_t)blockIdx.x * N_SP;
    int tid = threadIdx.x;
    float v0 = __bfloat162float(p[tid]);
    float v1 = __bfloat162float(p[tid + 256]);
    float v2 = __bfloat162float(p[tid + 512]);
    float v3 = __bfloat162float(p[tid + 768]);
    red[tid] = fmaxf(fmaxf(v0, v1), fmaxf(v2, v3));
    __syncthreads();
    for (int s = 128; s > 0; s >>= 1) { if (tid < s) red[tid] = fmaxf(red[tid], red[tid + s]); __syncthreads(); }
    float mx = red[0];
    __syncthreads();
    float d0 = fmaxf(fminf(v0 - mx, 0.f), -80.f);
    float d1 = fmaxf(fminf(v1 - mx, 0.f), -80.f);
    float d2 = fmaxf(fminf(v2 - mx, 0.f), -80.f);
    float d3 = fmaxf(fminf(v3 - mx, 0.f), -80.f);
    float e0 = __expf(d0), e1 = __expf(d1), e2 = __expf(d2), e3 = __expf(d3);
    red[tid] = e0 + e1 + e2 + e3;
    __syncthreads();
    for (int s = 128; s > 0; s >>= 1) { if (tid < s) red[tid] += red[tid + s]; __syncthreads(); }
    float inv = 1.f / red[0];
    p[tid]       = __float2bfloat16(e0 * inv);
    p[tid + 256] = __float2bfloat16(e1 * inv);
    p[tid + 512] = __float2bfloat16(e2 * inv);
    p[tid + 768] = __float2bfloat16(e3 * inv);
}

// ---------------------------------------------------------------------------
// K5: out[b][c][m] = gamma * sum_n Yv[c][n] * P[m][n] + x[b][c][m]
// Output dtype follows detected input dtype.
// Sentinel on NaN: 5555 + 1000*flag (5555 = bf16 path, 6555 = fp32 path).
// ---------------------------------------------------------------------------
__global__ __launch_bounds__(256) void k_out(
    const bf16* __restrict__ Y, const bf16* __restrict__ P,
    const void* __restrict__ x, const void* __restrict__ gamma,
    const int* __restrict__ flag, void* __restrict__ out, int batch0)
{
    __shared__ float As[16][132];   // [nk][c]
    __shared__ float Bs[16][132];   // [nk][m]
    int f32 = *flag;
    int bl = blockIdx.z, c0 = blockIdx.y * 128, m0 = blockIdx.x * 128;
    int tid = threadIdx.x, tx = tid & 15, ty = tid >> 4;
    const bf16* Yv = Y + (size_t)bl * R_ALL * N_SP + (size_t)128 * N_SP;
    const bf16* Pb = P + (size_t)bl * N_SP * N_SP;
    float acc[8][8];
#pragma unroll
    for (int i = 0; i < 8; ++i)
#pragma unroll
        for (int j = 0; j < 8; ++j) acc[i][j] = 0.f;

    for (int k0 = 0; k0 < N_SP; k0 += 16) {
#pragma unroll
        for (int i = 0; i < 8; ++i) {
            int idx = tid + i * 256; int rr = idx >> 4; int nk = idx & 15;
            As[nk][rr] = __bfloat162float(Yv[(size_t)(c0 + rr) * N_SP + k0 + nk]);
            Bs[nk][rr] = __bfloat162float(Pb[(size_t)(m0 + rr) * N_SP + k0 + nk]);
        }
        __syncthreads();
#pragma unroll
        for (int nk = 0; nk < 16; ++nk) {
            float av[8], bv8[8];
#pragma unroll
            for (int i = 0; i < 8; ++i) av[i] = As[nk][ty * 8 + i];
#pragma unroll
            for (int j = 0; j < 8; ++j) bv8[j] = Bs[nk][tx * 8 + j];
#pragma unroll
            for (int i = 0; i < 8; ++i)
#pragma unroll
                for (int j = 0; j < 8; ++j) acc[i][j] = fmaf(av[i], bv8[j], acc[i][j]);
        }
        __syncthreads();
    }
    float g = ldmix(gamma, 0, f32);
    const size_t base = (size_t)(batch0 + bl) * C_IN * N_SP;
#pragma unroll
    for (int i = 0; i < 8; ++i) {
        int c = c0 + ty * 8 + i;
#pragma unroll
        for (int j = 0; j < 8; ++j) {
            int m = m0 + tx * 8 + j;
            size_t o = base + (size_t)c * N_SP + m;
            float r = fmaf(g, acc[i][j], ldmix(x, o, f32));
            if (!(r == r)) r = 5555.0f + 1000.0f * f32;   // NaN sentinel
            stmix(out, o, r, f32);
        }
    }
}

// Diagnostic: workspace too small even for GB=1.
__global__ void k_wsfail(float* __restrict__ out, int n)
{
    int i = blockIdx.x * 256 + threadIdx.x;
    if (i < n) out[i] = 7777.0f;
}

// ---------------------------------------------------------------------------
extern "C" void kernel_launch(void* const* d_in, const int* in_sizes, int n_in,
                              void* d_out, int out_size, void* d_ws, size_t ws_size,
                              hipStream_t stream)
{
    const void* x  = d_in[0];
    const void* Wq = d_in[1];
    const void* bq = d_in[2];
    const void* uq = d_in[3];
    const void* Wk = d_in[4];
    const void* bk = d_in[5];
    const void* uk = d_in[6];
    const void* Wv = d_in[7];
    const void* bv = d_in[8];
    const void* uv = d_in[9];
    const void* gm = d_in[10];

    // workspace: flag int @0, sig[3] fp32 @16, pad 256 B; then per-group Y+S.
    const size_t perY = (size_t)R_ALL * N_SP * 2;   // 1,310,720 B
    const size_t perS = (size_t)N_SP * N_SP * 2;    // 2,097,152 B
    const size_t per  = perY + perS;                // 3,407,872 B
    int GB = 0;
    for (int g = 8; g >= 1; g >>= 1)
        if (256 + (size_t)g * per <= ws_size) { GB = g; break; }
    if (GB == 0) {
        k_wsfail<<<(out_size + 255) / 256, 256, 0, stream>>>((float*)d_out, out_size);
        return;
    }
    char* ws = (char*)d_ws;
    int*   flag = (int*)ws;
    float* sig  = (float*)(ws + 16);
    bf16*  Yb   = (bf16*)(ws + 256);
    bf16*  Sb   = (bf16*)(ws + 256 + (size_t)GB * perY);

    k_detect<<<1, 256, 0, stream>>>((const unsigned short*)x, flag);
    k_spectral<<<3, 512, 0, stream>>>(Wq, uq, Wk, uk, Wv, uv, flag, sig);
    for (int b0 = 0; b0 < BATCH; b0 += GB) {
        k_qkv<<<dim3(8, 10, GB), 256, 0, stream>>>(Wq, bq, Wk, bk, Wv, bv, sig, flag, x, Yb, b0);
        k_qk<<<dim3(8, 8, GB), 256, 0, stream>>>(Yb, Sb);
        k_softmax<<<GB * N_SP, 256, 0, stream>>>(Sb);
        k_out<<<dim3(8, 4, GB), 256, 0, stream>>>(Yb, Sb, x, gm, flag, d_out, b0);
    }
}

// Round 6
// 1208.325 us; speedup vs baseline: 1.3564x; 1.3564x over previous
//
#include <hip/hip_runtime.h>
#include <hip/hip_bf16.h>

typedef __hip_bfloat16 bf16;
typedef __bf16 bf16x8 __attribute__((ext_vector_type(8)));
typedef float  f32x4  __attribute__((ext_vector_type(4)));

#define C_IN  512
#define N_SP  1024
#define R_ALL 640   // rows 0..63 = q, 64..127 = k, 128..639 = v
#define BATCH 32

// Mixed-dtype accessors: f32 flag selects fp32 or bf16 view of the SAME buffer.
__device__ __forceinline__ float ldmix(const void* p, size_t i, int f32) {
    return f32 ? ((const float*)p)[i] : __bfloat162float(((const bf16*)p)[i]);
}
__device__ __forceinline__ void stmix(void* p, size_t i, float v, int f32) {
    if (f32) ((float*)p)[i] = v;
    else     ((bf16*)p)[i] = __float2bfloat16(v);
}

// ---------------------------------------------------------------------------
// K0: dtype detector (even halfwords = fp32 low-mantissa garbage vs real bf16).
// Writes flag: 1 = fp32, 0 = bf16.
// ---------------------------------------------------------------------------
__global__ void k_detect(const unsigned short* __restrict__ xh, int* __restrict__ flag)
{
    __shared__ int red[256];
    int tid = threadIdx.x;
    unsigned short h = xh[2 * tid];
    int e = (h >> 7) & 0xFF;
    int plaus = (e == 0 || (e >= 96 && e <= 159)) ? 1 : 0;
    red[tid] = plaus;
    __syncthreads();
    for (int s = 128; s > 0; s >>= 1) { if (tid < s) red[tid] += red[tid + s]; __syncthreads(); }
    if (tid == 0) *flag = (red[0] < 192) ? 1 : 0;
}

// ---------------------------------------------------------------------------
// K1: spectral norm — 1/sigma per matrix. UNROLLED (was 900-cyc/iter
// latency-bound: 193 us; unroll 16 -> ~16 outstanding loads -> ~15 us).
// ---------------------------------------------------------------------------
__global__ __launch_bounds__(512) void k_spectral(
    const void* __restrict__ Wq, const void* __restrict__ uq,
    const void* __restrict__ Wk, const void* __restrict__ uk,
    const void* __restrict__ Wv, const void* __restrict__ uv,
    const int* __restrict__ flag, float* __restrict__ sig)
{
    __shared__ float sh_u[512];
    __shared__ float sh_v[512];
    __shared__ float sh_red[512];
    int f32 = *flag;
    const void *W, *u; int out;
    if (blockIdx.x == 0)      { W = Wq; u = uq; out = 64;  }
    else if (blockIdx.x == 1) { W = Wk; u = uk; out = 64;  }
    else                      { W = Wv; u = uv; out = 512; }
    int tid = threadIdx.x;
    if (tid < out) sh_u[tid] = ldmix(u, tid, f32);
    __syncthreads();

    float vacc = 0.f;
#pragma unroll 16
    for (int o = 0; o < out; ++o)
        vacc += ldmix(W, (size_t)o * C_IN + tid, f32) * sh_u[o];
    sh_red[tid] = vacc * vacc;
    __syncthreads();
    for (int s = 256; s > 0; s >>= 1) { if (tid < s) sh_red[tid] += sh_red[tid + s]; __syncthreads(); }
    float vinv = 1.f / sqrtf(sh_red[0]);
    __syncthreads();
    sh_v[tid] = vacc * vinv;
    __syncthreads();

    float t = 0.f;
    if (tid < out) {
#pragma unroll 16
        for (int c = 0; c < C_IN; ++c)
            t += ldmix(W, (size_t)tid * C_IN + c, f32) * sh_v[c];
    }
    sh_red[tid] = (tid < out) ? t * t : 0.f;
    __syncthreads();
    for (int s = 256; s > 0; s >>= 1) { if (tid < s) sh_red[tid] += sh_red[tid + s]; __syncthreads(); }
    if (tid == 0) sig[blockIdx.x] = 1.f / sqrtf(sh_red[0]);
}

// ---------------------------------------------------------------------------
// K2: QKV projection (fp32 vector GEMM — MFMA conversion next round).
// Y[bl][r][n] = (1/sigma) * sum_c W[r][c] * x[batch0+bl][c][n] + b[r]
// ---------------------------------------------------------------------------
__global__ __launch_bounds__(256) void k_qkv(
    const void* __restrict__ Wq, const void* __restrict__ bq,
    const void* __restrict__ Wk, const void* __restrict__ bk,
    const void* __restrict__ Wv, const void* __restrict__ bv,
    const float* __restrict__ sig, const int* __restrict__ flag,
    const void* __restrict__ x, bf16* __restrict__ Y, int batch0)
{
    __shared__ float As[16][64 + 4];    // [k][r]
    __shared__ float Bs[16][128 + 4];   // [k][n]
    int f32 = *flag;
    int bl = blockIdx.z;
    int r0 = blockIdx.y * 64;
    int n0 = blockIdx.x * 128;
    const void *Wt, *bt; float sc; int rbase;
    if (blockIdx.y == 0)      { Wt = Wq; bt = bq; sc = sig[0]; rbase = 0; }
    else if (blockIdx.y == 1) { Wt = Wk; bt = bk; sc = sig[1]; rbase = 0; }
    else                      { Wt = Wv; bt = bv; sc = sig[2]; rbase = (blockIdx.y - 2) * 64; }
    int tid = threadIdx.x, tx = tid & 15, ty = tid >> 4;
    const size_t xoff = (size_t)(batch0 + bl) * C_IN * N_SP;
    bf16* Yb = Y + (size_t)bl * R_ALL * N_SP;
    float acc[4][8];
#pragma unroll
    for (int i = 0; i < 4; ++i)
#pragma unroll
        for (int j = 0; j < 8; ++j) acc[i][j] = 0.f;

    for (int k0 = 0; k0 < C_IN; k0 += 16) {
#pragma unroll
        for (int i = 0; i < 4; ++i) {
            int idx = tid + i * 256; int r = idx >> 4; int kk = idx & 15;
            As[kk][r] = ldmix(Wt, (size_t)(rbase + r) * C_IN + k0 + kk, f32) * sc;
        }
#pragma unroll
        for (int i = 0; i < 8; ++i) {
            int idx = tid + i * 256; int kk = idx >> 7; int nn = idx & 127;
            Bs[kk][nn] = ldmix(x, xoff + (size_t)(k0 + kk) * N_SP + n0 + nn, f32);
        }
        __syncthreads();
#pragma unroll
        for (int kk = 0; kk < 16; ++kk) {
            float av[4], bv8[8];
#pragma unroll
            for (int i = 0; i < 4; ++i) av[i] = As[kk][ty * 4 + i];
#pragma unroll
            for (int j = 0; j < 8; ++j) bv8[j] = Bs[kk][tx * 8 + j];
#pragma unroll
            for (int i = 0; i < 4; ++i)
#pragma unroll
                for (int j = 0; j < 8; ++j) acc[i][j] = fmaf(av[i], bv8[j], acc[i][j]);
        }
        __syncthreads();
    }
#pragma unroll
    for (int i = 0; i < 4; ++i) {
        int rl = ty * 4 + i;
        float bi = ldmix(bt, rbase + rl, f32);
#pragma unroll
        for (int j = 0; j < 8; ++j)
            Yb[(size_t)(r0 + rl) * N_SP + n0 + tx * 8 + j] = __float2bfloat16(acc[i][j] + bi);
    }
}

// ---------------------------------------------------------------------------
// K3: scores.  S[bl][m][n] = sum_{o<64} Yk[o][m] * Yq[o][n]   (S[m,n]=qk[n,m])
// ---------------------------------------------------------------------------
__global__ __launch_bounds__(256) void k_qk(const bf16* __restrict__ Y, bf16* __restrict__ S)
{
    __shared__ float As[16][132];   // [o][m]
    __shared__ float Bs[16][132];   // [o][n]
    int bl = blockIdx.z, m0 = blockIdx.y * 128, n0 = blockIdx.x * 128;
    int tid = threadIdx.x, tx = tid & 15, ty = tid >> 4;
    const bf16* Yb = Y + (size_t)bl * R_ALL * N_SP;
    float acc[8][8];
#pragma unroll
    for (int i = 0; i < 8; ++i)
#pragma unroll
        for (int j = 0; j < 8; ++j) acc[i][j] = 0.f;

    for (int k0 = 0; k0 < 64; k0 += 16) {
#pragma unroll
        for (int i = 0; i < 8; ++i) {
            int idx = tid + i * 256; int o = idx >> 7; int mm = idx & 127;
            As[o][mm] = __bfloat162float(Yb[(size_t)(64 + k0 + o) * N_SP + m0 + mm]);
            Bs[o][mm] = __bfloat162float(Yb[(size_t)(k0 + o) * N_SP + n0 + mm]);
        }
        __syncthreads();
#pragma unroll
        for (int o = 0; o < 16; ++o) {
            float av[8], bv8[8];
#pragma unroll
            for (int i = 0; i < 8; ++i) av[i] = As[o][ty * 8 + i];
#pragma unroll
            for (int j = 0; j < 8; ++j) bv8[j] = Bs[o][tx * 8 + j];
#pragma unroll
            for (int i = 0; i < 8; ++i)
#pragma unroll
                for (int j = 0; j < 8; ++j) acc[i][j] = fmaf(av[i], bv8[j], acc[i][j]);
        }
        __syncthreads();
    }
    bf16* Sb = S + (size_t)bl * N_SP * N_SP;
#pragma unroll
    for (int i = 0; i < 8; ++i)
#pragma unroll
        for (int j = 0; j < 8; ++j)
            Sb[(size_t)(m0 + ty * 8 + i) * N_SP + n0 + tx * 8 + j] = __float2bfloat16(acc[i][j]);
}

// ---------------------------------------------------------------------------
// K4: row softmax of S (over n), in place.  Exponent clamped (NaN-eating).
// ---------------------------------------------------------------------------
__global__ __launch_bounds__(256) void k_softmax(bf16* __restrict__ S)
{
    __shared__ float red[256];
    bf16* p = S + (size_t)blockIdx.x * N_SP;
    int tid = threadIdx.x;
    float v0 = __bfloat162float(p[tid]);
    float v1 = __bfloat162float(p[tid + 256]);
    float v2 = __bfloat162float(p[tid + 512]);
    float v3 = __bfloat162float(p[tid + 768]);
    red[tid] = fmaxf(fmaxf(v0, v1), fmaxf(v2, v3));
    __syncthreads();
    for (int s = 128; s > 0; s >>= 1) { if (tid < s) red[tid] = fmaxf(red[tid], red[tid + s]); __syncthreads(); }
    float mx = red[0];
    __syncthreads();
    float d0 = fmaxf(fminf(v0 - mx, 0.f), -80.f);
    float d1 = fmaxf(fminf(v1 - mx, 0.f), -80.f);
    float d2 = fmaxf(fminf(v2 - mx, 0.f), -80.f);
    float d3 = fmaxf(fminf(v3 - mx, 0.f), -80.f);
    float e0 = __expf(d0), e1 = __expf(d1), e2 = __expf(d2), e3 = __expf(d3);
    red[tid] = e0 + e1 + e2 + e3;
    __syncthreads();
    for (int s = 128; s > 0; s >>= 1) { if (tid < s) red[tid] += red[tid + s]; __syncthreads(); }
    float inv = 1.f / red[0];
    p[tid]       = __float2bfloat16(e0 * inv);
    p[tid + 256] = __float2bfloat16(e1 * inv);
    p[tid + 512] = __float2bfloat16(e2 * inv);
    p[tid + 768] = __float2bfloat16(e3 * inv);
}

// ---------------------------------------------------------------------------
// K5 (MFMA): out[b][c][m] = gamma * sum_n Yv[c][n] * P[m][n] + x[b][c][m]
// gemm-BT: A = Yv [c][n] K-fastest, B^T = P [m][n] K-fastest.
// 128x128 block tile, BK=32, 4 waves x (4x4) mfma_f32_16x16x32_bf16.
// LDS rows padded to 40 bf16 (80 B: 16B-aligned, 2-way bank alias = free).
// A-frag: [m=lane&15][k=quad*8+j]; D: row=quad*4+reg, col=lane&15 (m89/m91).
// ---------------------------------------------------------------------------
__global__ __launch_bounds__(256) void k_out(
    const bf16* __restrict__ Y, const bf16* __restrict__ P,
    const void* __restrict__ x, const void* __restrict__ gamma,
    const int* __restrict__ flag, void* __restrict__ out, int batch0)
{
    __shared__ __bf16 Als[128][40];   // [c-row][k] pad 32->40
    __shared__ __bf16 Bls[128][40];   // [m-row][k]
    int f32 = *flag;
    int bl = blockIdx.z, c0 = blockIdx.y * 128, m0 = blockIdx.x * 128;
    int tid = threadIdx.x;
    int wave = tid >> 6, lane = tid & 63, quad = lane >> 4, l16 = lane & 15;
    int wc = (wave >> 1) * 64;        // wave c-offset within block tile
    int wm = (wave & 1) * 64;         // wave m-offset
    const bf16* Yv = Y + (size_t)bl * R_ALL * N_SP + (size_t)128 * N_SP;
    const bf16* Pb = P + (size_t)bl * N_SP * N_SP;

    f32x4 acc[4][4];
#pragma unroll
    for (int i = 0; i < 4; ++i)
#pragma unroll
        for (int j = 0; j < 4; ++j) acc[i][j] = (f32x4){0.f, 0.f, 0.f, 0.f};

    for (int k0 = 0; k0 < N_SP; k0 += 32) {
        // stage A (Yv) and B (P) tiles: 128 rows x 32 bf16, uint4 (16 B) loads
#pragma unroll
        for (int s = 0; s < 2; ++s) {
            int idx = tid + s * 256;          // 0..511
            int row = idx >> 2, ch = idx & 3; // 128 rows x 4 chunks of 8 bf16
            *reinterpret_cast<uint4*>(&Als[row][ch * 8]) =
                *reinterpret_cast<const uint4*>(&Yv[(size_t)(c0 + row) * N_SP + k0 + ch * 8]);
            *reinterpret_cast<uint4*>(&Bls[row][ch * 8]) =
                *reinterpret_cast<const uint4*>(&Pb[(size_t)(m0 + row) * N_SP + k0 + ch * 8]);
        }
        __syncthreads();
        bf16x8 a[4], b[4];
#pragma unroll
        for (int i = 0; i < 4; ++i)
            a[i] = *reinterpret_cast<const bf16x8*>(&Als[wc + i * 16 + l16][quad * 8]);
#pragma unroll
        for (int j = 0; j < 4; ++j)
            b[j] = *reinterpret_cast<const bf16x8*>(&Bls[wm + j * 16 + l16][quad * 8]);
#pragma unroll
        for (int i = 0; i < 4; ++i)
#pragma unroll
            for (int j = 0; j < 4; ++j)
                acc[i][j] = __builtin_amdgcn_mfma_f32_16x16x32_bf16(a[i], b[j], acc[i][j], 0, 0, 0);
        __syncthreads();
    }

    float g = ldmix(gamma, 0, f32);
    const size_t base = (size_t)(batch0 + bl) * C_IN * N_SP;
#pragma unroll
    for (int i = 0; i < 4; ++i) {
#pragma unroll
        for (int j = 0; j < 4; ++j) {
#pragma unroll
            for (int r = 0; r < 4; ++r) {
                int c = c0 + wc + i * 16 + quad * 4 + r;
                int m = m0 + wm + j * 16 + l16;
                size_t o = base + (size_t)c * N_SP + m;
                float v = fmaf(g, acc[i][j][r], ldmix(x, o, f32));
                if (!(v == v)) v = 5555.0f + 1000.0f * f32;   // NaN sentinel
                stmix(out, o, v, f32);
            }
        }
    }
}

// Diagnostic: workspace too small even for GB=1.
__global__ void k_wsfail(float* __restrict__ out, int n)
{
    int i = blockIdx.x * 256 + threadIdx.x;
    if (i < n) out[i] = 7777.0f;
}

// ---------------------------------------------------------------------------
extern "C" void kernel_launch(void* const* d_in, const int* in_sizes, int n_in,
                              void* d_out, int out_size, void* d_ws, size_t ws_size,
                              hipStream_t stream)
{
    const void* x  = d_in[0];
    const void* Wq = d_in[1];
    const void* bq = d_in[2];
    const void* uq = d_in[3];
    const void* Wk = d_in[4];
    const void* bk = d_in[5];
    const void* uk = d_in[6];
    const void* Wv = d_in[7];
    const void* bv = d_in[8];
    const void* uv = d_in[9];
    const void* gm = d_in[10];

    // workspace: flag int @0, sig[3] fp32 @16, pad 256 B; then per-group Y+S.
    const size_t perY = (size_t)R_ALL * N_SP * 2;   // 1,310,720 B
    const size_t perS = (size_t)N_SP * N_SP * 2;    // 2,097,152 B
    const size_t per  = perY + perS;                // 3,407,872 B
    int GB = 0;
    for (int g = 8; g >= 1; g >>= 1)
        if (256 + (size_t)g * per <= ws_size) { GB = g; break; }
    if (GB == 0) {
        k_wsfail<<<(out_size + 255) / 256, 256, 0, stream>>>((float*)d_out, out_size);
        return;
    }
    char* ws = (char*)d_ws;
    int*   flag = (int*)ws;
    float* sig  = (float*)(ws + 16);
    bf16*  Yb   = (bf16*)(ws + 256);
    bf16*  Sb   = (bf16*)(ws + 256 + (size_t)GB * perY);

    k_detect<<<1, 256, 0, stream>>>((const unsigned short*)x, flag);
    k_spectral<<<3, 512, 0, stream>>>(Wq, uq, Wk, uk, Wv, uv, flag, sig);
    for (int b0 = 0; b0 < BATCH; b0 += GB) {
        k_qkv<<<dim3(8, 10, GB), 256, 0, stream>>>(Wq, bq, Wk, bk, Wv, bv, sig, flag, x, Yb, b0);
        k_qk<<<dim3(8, 8, GB), 256, 0, stream>>>(Yb, Sb);
        k_softmax<<<GB * N_SP, 256, 0, stream>>>(Sb);
        k_out<<<dim3(8, 4, GB), 256, 0, stream>>>(Yb, Sb, x, gm, flag, d_out, b0);
    }
}

// Round 7
// 664.542 us; speedup vs baseline: 2.4663x; 1.8183x over previous
//
#include <hip/hip_runtime.h>
#include <hip/hip_bf16.h>

typedef __hip_bfloat16 bf16;
typedef __bf16 bf16x8 __attribute__((ext_vector_type(8)));
typedef float  f32x4  __attribute__((ext_vector_type(4)));

#define C_IN  512
#define N_SP  1024
#define BATCH 32

// Mixed-dtype accessors: f32 flag selects fp32 or bf16 view of the SAME buffer.
__device__ __forceinline__ float ldmix(const void* p, size_t i, int f32) {
    return f32 ? ((const float*)p)[i] : __bfloat162float(((const bf16*)p)[i]);
}
__device__ __forceinline__ void stmix(void* p, size_t i, float v, int f32) {
    if (f32) ((float*)p)[i] = v;
    else     ((bf16*)p)[i] = __float2bfloat16(v);
}
__device__ __forceinline__ unsigned short bfbits(float f) {
    bf16 t = __float2bfloat16(f);
    return *reinterpret_cast<unsigned short*>(&t);
}

// ---------------------------------------------------------------------------
// K0: dtype detector (even halfwords = fp32 low-mantissa garbage vs real bf16).
// ---------------------------------------------------------------------------
__global__ void k_detect(const unsigned short* __restrict__ xh, int* __restrict__ flag)
{
    __shared__ int red[256];
    int tid = threadIdx.x;
    unsigned short h = xh[2 * tid];
    int e = (h >> 7) & 0xFF;
    red[tid] = (e == 0 || (e >= 96 && e <= 159)) ? 1 : 0;
    __syncthreads();
    for (int s = 128; s > 0; s >>= 1) { if (tid < s) red[tid] += red[tid + s]; __syncthreads(); }
    if (tid == 0) *flag = (red[0] < 192) ? 1 : 0;
}

// ---------------------------------------------------------------------------
// K1: spectral norm — 1/sigma per matrix (unrolled for MLP latency hiding).
// ---------------------------------------------------------------------------
__global__ __launch_bounds__(512) void k_spectral(
    const void* __restrict__ Wq, const void* __restrict__ uq,
    const void* __restrict__ Wk, const void* __restrict__ uk,
    const void* __restrict__ Wv, const void* __restrict__ uv,
    const int* __restrict__ flag, float* __restrict__ sig)
{
    __shared__ float sh_u[512];
    __shared__ float sh_v[512];
    __shared__ float sh_red[512];
    int f32 = *flag;
    const void *W, *u; int out;
    if (blockIdx.x == 0)      { W = Wq; u = uq; out = 64;  }
    else if (blockIdx.x == 1) { W = Wk; u = uk; out = 64;  }
    else                      { W = Wv; u = uv; out = 512; }
    int tid = threadIdx.x;
    if (tid < out) sh_u[tid] = ldmix(u, tid, f32);
    __syncthreads();

    float vacc = 0.f;
#pragma unroll 16
    for (int o = 0; o < out; ++o)
        vacc += ldmix(W, (size_t)o * C_IN + tid, f32) * sh_u[o];
    sh_red[tid] = vacc * vacc;
    __syncthreads();
    for (int s = 256; s > 0; s >>= 1) { if (tid < s) sh_red[tid] += sh_red[tid + s]; __syncthreads(); }
    float vinv = 1.f / sqrtf(sh_red[0]);
    __syncthreads();
    sh_v[tid] = vacc * vinv;
    __syncthreads();

    float t = 0.f;
    if (tid < out) {
#pragma unroll 16
        for (int c = 0; c < C_IN; ++c)
            t += ldmix(W, (size_t)tid * C_IN + c, f32) * sh_v[c];
    }
    sh_red[tid] = (tid < out) ? t * t : 0.f;
    __syncthreads();
    for (int s = 256; s > 0; s >>= 1) { if (tid < s) sh_red[tid] += sh_red[tid + s]; __syncthreads(); }
    if (tid == 0) sig[blockIdx.x] = 1.f / sqrtf(sh_red[0]);
}

// ---------------------------------------------------------------------------
// K2: weight prep. Wb[640][512] = bf16(W * 1/sigma) stacked (q,k,v).
// For q/k rows (<128) also Wlo = bf16(residual) for split-bf16 GEMM.
// biasf fp32[640].
// ---------------------------------------------------------------------------
__global__ __launch_bounds__(256) void k_wscale(
    const void* __restrict__ Wq, const void* __restrict__ bq,
    const void* __restrict__ Wk, const void* __restrict__ bk,
    const void* __restrict__ Wv, const void* __restrict__ bv,
    const float* __restrict__ sig, const int* __restrict__ flag,
    bf16* __restrict__ Wb, bf16* __restrict__ Wlo, float* __restrict__ biasf)
{
    int f32 = *flag;
    int r = blockIdx.x;            // 0..639
    const void *W, *b; int row; float s;
    if (r < 64)       { W = Wq; b = bq; row = r;       s = sig[0]; }
    else if (r < 128) { W = Wk; b = bk; row = r - 64;  s = sig[1]; }
    else              { W = Wv; b = bv; row = r - 128; s = sig[2]; }
    for (int c = threadIdx.x; c < C_IN; c += 256) {
        float w = ldmix(W, (size_t)row * C_IN + c, f32) * s;
        bf16 hi = __float2bfloat16(w);
        Wb[(size_t)r * C_IN + c] = hi;
        if (r < 128)
            Wlo[(size_t)r * C_IN + c] = __float2bfloat16(w - __bfloat162float(hi));
    }
    if (threadIdx.x == 0) biasf[r] = ldmix(b, row, f32);
}

// ---------------------------------------------------------------------------
// K3: transpose x[c][n] -> xT[n][c] as split bf16 (hi @ +0, lo @ +1MB).
// 64x64 tiles via LDS. One group-batch per blockIdx.z.
// ---------------------------------------------------------------------------
__global__ __launch_bounds__(256) void k_xt(
    const void* __restrict__ x, const int* __restrict__ flag,
    char* __restrict__ SX, int batch0)
{
    __shared__ float tile[64][65];
    int f32 = *flag;
    int z = blockIdx.z;
    int n0 = blockIdx.x * 64, c0 = blockIdx.y * 64;
    size_t xoff = (size_t)(batch0 + z) * C_IN * N_SP;
    bf16* xTh = (bf16*)(SX + (size_t)z * 4194304);
    bf16* xTl = xTh + 524288;
    int tid = threadIdx.x;
#pragma unroll
    for (int i = 0; i < 4; ++i) {
        int idx = tid + i * 256;           // 0..1023
        int c = idx >> 4, nq = idx & 15;
#pragma unroll
        for (int t = 0; t < 4; ++t)
            tile[c][nq * 4 + t] = ldmix(x, xoff + (size_t)(c0 + c) * N_SP + n0 + nq * 4 + t, f32);
    }
    __syncthreads();
#pragma unroll
    for (int i = 0; i < 16; ++i) {
        int idx = tid + i * 256;           // 0..4095
        int n = idx >> 6, c = idx & 63;
        float v = tile[c][n];
        bf16 hi = __float2bfloat16(v);
        xTh[(size_t)(n0 + n) * C_IN + c0 + c] = hi;
        xTl[(size_t)(n0 + n) * C_IN + c0 + c] = __float2bfloat16(v - __bfloat162float(hi));
    }
}

// ---------------------------------------------------------------------------
// K4: v-projection MFMA. Yv[c][n] = sum_k Wb[128+c][k] * xT[n][k] + bias.
// 128x128 tile, BK=32, 4 waves x 4x4 mfma_f32_16x16x32_bf16 (proven k_out
// structure). Both operands K-fastest.
// ---------------------------------------------------------------------------
__global__ __launch_bounds__(256) void k_qkv_v(
    const bf16* __restrict__ Wb, const float* __restrict__ biasf,
    const char* __restrict__ SX, bf16* __restrict__ YV)
{
    __shared__ __bf16 Als[128][40];
    __shared__ __bf16 Bls[128][40];
    int z = blockIdx.z;
    int n0 = blockIdx.x * 128;
    int r0 = 128 + blockIdx.y * 128;       // global W row (v band)
    const bf16* xTh = (const bf16*)(SX + (size_t)z * 4194304);
    bf16* Yv = YV + (size_t)z * 524288;
    int tid = threadIdx.x, wave = tid >> 6, lane = tid & 63, quad = lane >> 4, l16 = lane & 15;
    int wc = (wave >> 1) * 64, wm = (wave & 1) * 64;

    f32x4 acc[4][4];
#pragma unroll
    for (int i = 0; i < 4; ++i)
#pragma unroll
        for (int j = 0; j < 4; ++j) acc[i][j] = (f32x4){0.f, 0.f, 0.f, 0.f};

    for (int k0 = 0; k0 < C_IN; k0 += 32) {
#pragma unroll
        for (int s = 0; s < 2; ++s) {
            int idx = tid + s * 256; int row = idx >> 2, ch = idx & 3;
            *reinterpret_cast<uint4*>(&Als[row][ch * 8]) =
                *reinterpret_cast<const uint4*>(&Wb[(size_t)(r0 + row) * C_IN + k0 + ch * 8]);
            *reinterpret_cast<uint4*>(&Bls[row][ch * 8]) =
                *reinterpret_cast<const uint4*>(&xTh[(size_t)(n0 + row) * C_IN + k0 + ch * 8]);
        }
        __syncthreads();
        bf16x8 a[4], b[4];
#pragma unroll
        for (int i = 0; i < 4; ++i)
            a[i] = *reinterpret_cast<const bf16x8*>(&Als[wc + i * 16 + l16][quad * 8]);
#pragma unroll
        for (int j = 0; j < 4; ++j)
            b[j] = *reinterpret_cast<const bf16x8*>(&Bls[wm + j * 16 + l16][quad * 8]);
#pragma unroll
        for (int i = 0; i < 4; ++i)
#pragma unroll
            for (int j = 0; j < 4; ++j)
                acc[i][j] = __builtin_amdgcn_mfma_f32_16x16x32_bf16(a[i], b[j], acc[i][j], 0, 0, 0);
        __syncthreads();
    }
#pragma unroll
    for (int i = 0; i < 4; ++i)
#pragma unroll
        for (int j = 0; j < 4; ++j)
#pragma unroll
            for (int r = 0; r < 4; ++r) {
                int c = r0 + wc + i * 16 + quad * 4 + r;        // global W row
                int n = n0 + wm + j * 16 + l16;
                Yv[(size_t)(c - 128) * N_SP + n] = __float2bfloat16(acc[i][j][r] + biasf[c]);
            }
}

// ---------------------------------------------------------------------------
// K5: q/k projection, split-bf16 MFMA (AhBh + AhBl + AlBh ~ fp32 product).
// 64x64 tile (m0: 0=q band, 64=k band), BK=32, 4 waves x 2x2 tiles.
// Output stored TRANSPOSED: qt/kt[n][o] (o fastest) for the QK^T MFMA.
// ---------------------------------------------------------------------------
__global__ __launch_bounds__(256) void k_qkv_qk(
    const bf16* __restrict__ Wb, const bf16* __restrict__ Wlo,
    const float* __restrict__ biasf, const char* __restrict__ SX,
    bf16* __restrict__ QT, bf16* __restrict__ KT)
{
    __shared__ __bf16 Ah[64][40], Al[64][40], Bh[64][40], Bl[64][40];
    int z = blockIdx.z;
    int n0 = blockIdx.x * 64;
    int m0 = blockIdx.y * 64;              // 0 -> q rows, 64 -> k rows
    const bf16* xTh = (const bf16*)(SX + (size_t)z * 4194304);
    const bf16* xTl = xTh + 524288;
    bf16* qt = QT + (size_t)z * 65536;
    bf16* kt = KT + (size_t)z * 65536;
    int tid = threadIdx.x, wave = tid >> 6, lane = tid & 63, quad = lane >> 4, l16 = lane & 15;
    int wmh = (wave >> 1) * 32, wnh = (wave & 1) * 32;

    f32x4 acc[2][2];
#pragma unroll
    for (int i = 0; i < 2; ++i)
#pragma unroll
        for (int j = 0; j < 2; ++j) acc[i][j] = (f32x4){0.f, 0.f, 0.f, 0.f};

    for (int k0 = 0; k0 < C_IN; k0 += 32) {
        int row = tid >> 2, ch = tid & 3;  // 64 rows x 4 chunks, exactly 256
        *reinterpret_cast<uint4*>(&Ah[row][ch * 8]) =
            *reinterpret_cast<const uint4*>(&Wb[(size_t)(m0 + row) * C_IN + k0 + ch * 8]);
        *reinterpret_cast<uint4*>(&Al[row][ch * 8]) =
            *reinterpret_cast<const uint4*>(&Wlo[(size_t)(m0 + row) * C_IN + k0 + ch * 8]);
        *reinterpret_cast<uint4*>(&Bh[row][ch * 8]) =
            *reinterpret_cast<const uint4*>(&xTh[(size_t)(n0 + row) * C_IN + k0 + ch * 8]);
        *reinterpret_cast<uint4*>(&Bl[row][ch * 8]) =
            *reinterpret_cast<const uint4*>(&xTl[(size_t)(n0 + row) * C_IN + k0 + ch * 8]);
        __syncthreads();
        bf16x8 ah[2], al[2], bh[2], bl[2];
#pragma unroll
        for (int i = 0; i < 2; ++i) {
            ah[i] = *reinterpret_cast<const bf16x8*>(&Ah[wmh + i * 16 + l16][quad * 8]);
            al[i] = *reinterpret_cast<const bf16x8*>(&Al[wmh + i * 16 + l16][quad * 8]);
        }
#pragma unroll
        for (int j = 0; j < 2; ++j) {
            bh[j] = *reinterpret_cast<const bf16x8*>(&Bh[wnh + j * 16 + l16][quad * 8]);
            bl[j] = *reinterpret_cast<const bf16x8*>(&Bl[wnh + j * 16 + l16][quad * 8]);
        }
#pragma unroll
        for (int i = 0; i < 2; ++i)
#pragma unroll
            for (int j = 0; j < 2; ++j) {
                acc[i][j] = __builtin_amdgcn_mfma_f32_16x16x32_bf16(ah[i], bh[j], acc[i][j], 0, 0, 0);
                acc[i][j] = __builtin_amdgcn_mfma_f32_16x16x32_bf16(ah[i], bl[j], acc[i][j], 0, 0, 0);
                acc[i][j] = __builtin_amdgcn_mfma_f32_16x16x32_bf16(al[i], bh[j], acc[i][j], 0, 0, 0);
            }
        __syncthreads();
    }
#pragma unroll
    for (int i = 0; i < 2; ++i)
#pragma unroll
        for (int j = 0; j < 2; ++j) {
            int cbase = m0 + wmh + i * 16 + quad * 4;       // global row, +r (4 consecutive)
            int n = n0 + wnh + j * 16 + l16;
            ushort4 st;
            st.x = bfbits(acc[i][j][0] + biasf[cbase + 0]);
            st.y = bfbits(acc[i][j][1] + biasf[cbase + 1]);
            st.z = bfbits(acc[i][j][2] + biasf[cbase + 2]);
            st.w = bfbits(acc[i][j][3] + biasf[cbase + 3]);
            bf16* dst = (m0 == 0) ? &qt[(size_t)n * 64 + cbase]
                                  : &kt[(size_t)n * 64 + (cbase - 64)];
            *reinterpret_cast<ushort4*>(dst) = st;           // 8 B, aligned
        }
}

// ---------------------------------------------------------------------------
// K6: scores MFMA. S[m][n] = sum_o kt[m][o] * qt[n][o], fp32 out (over dead xT).
// 128x128 tile, K=64 (2 x BK=32), 4 waves x 4x4.
// ---------------------------------------------------------------------------
__global__ __launch_bounds__(256) void k_qk(
    const bf16* __restrict__ QT, const bf16* __restrict__ KT,
    char* __restrict__ SX)
{
    __shared__ __bf16 Als[128][40];
    __shared__ __bf16 Bls[128][40];
    int z = blockIdx.z, m0 = blockIdx.y * 128, n0 = blockIdx.x * 128;
    const bf16* qt = QT + (size_t)z * 65536;
    const bf16* kt = KT + (size_t)z * 65536;
    float* Sf = (float*)(SX + (size_t)z * 4194304);
    int tid = threadIdx.x, wave = tid >> 6, lane = tid & 63, quad = lane >> 4, l16 = lane & 15;
    int wc = (wave >> 1) * 64, wm = (wave & 1) * 64;

    f32x4 acc[4][4];
#pragma unroll
    for (int i = 0; i < 4; ++i)
#pragma unroll
        for (int j = 0; j < 4; ++j) acc[i][j] = (f32x4){0.f, 0.f, 0.f, 0.f};

#pragma unroll
    for (int k0 = 0; k0 < 64; k0 += 32) {
#pragma unroll
        for (int s = 0; s < 2; ++s) {
            int idx = tid + s * 256; int row = idx >> 2, ch = idx & 3;
            *reinterpret_cast<uint4*>(&Als[row][ch * 8]) =
                *reinterpret_cast<const uint4*>(&kt[(size_t)(m0 + row) * 64 + k0 + ch * 8]);
            *reinterpret_cast<uint4*>(&Bls[row][ch * 8]) =
                *reinterpret_cast<const uint4*>(&qt[(size_t)(n0 + row) * 64 + k0 + ch * 8]);
        }
        __syncthreads();
        bf16x8 a[4], b[4];
#pragma unroll
        for (int i = 0; i < 4; ++i)
            a[i] = *reinterpret_cast<const bf16x8*>(&Als[wc + i * 16 + l16][quad * 8]);
#pragma unroll
        for (int j = 0; j < 4; ++j)
            b[j] = *reinterpret_cast<const bf16x8*>(&Bls[wm + j * 16 + l16][quad * 8]);
#pragma unroll
        for (int i = 0; i < 4; ++i)
#pragma unroll
            for (int j = 0; j < 4; ++j)
                acc[i][j] = __builtin_amdgcn_mfma_f32_16x16x32_bf16(a[i], b[j], acc[i][j], 0, 0, 0);
        __syncthreads();
    }
#pragma unroll
    for (int i = 0; i < 4; ++i)
#pragma unroll
        for (int j = 0; j < 4; ++j)
#pragma unroll
            for (int r = 0; r < 4; ++r) {
                int m = m0 + wc + i * 16 + quad * 4 + r;
                int n = n0 + wm + j * 16 + l16;
                Sf[(size_t)m * N_SP + n] = acc[i][j][r];
            }
}

// ---------------------------------------------------------------------------
// K7: row softmax, fp32 in -> bf16 P written IN PLACE (row owned by block;
// all reads complete before writes). P row pitch becomes 2048 bf16.
// ---------------------------------------------------------------------------
__global__ __launch_bounds__(256) void k_softmax(char* __restrict__ SX)
{
    __shared__ float red[256];
    int z = blockIdx.x >> 10, m = blockIdx.x & 1023;
    float* p = (float*)(SX + (size_t)z * 4194304) + (size_t)m * N_SP;
    bf16* pb = (bf16*)p;
    int tid = threadIdx.x;
    float v0 = p[tid], v1 = p[tid + 256], v2 = p[tid + 512], v3 = p[tid + 768];
    red[tid] = fmaxf(fmaxf(v0, v1), fmaxf(v2, v3));
    __syncthreads();
    for (int s = 128; s > 0; s >>= 1) { if (tid < s) red[tid] = fmaxf(red[tid], red[tid + s]); __syncthreads(); }
    float mx = red[0];
    __syncthreads();
    float d0 = fmaxf(fminf(v0 - mx, 0.f), -80.f);
    float d1 = fmaxf(fminf(v1 - mx, 0.f), -80.f);
    float d2 = fmaxf(fminf(v2 - mx, 0.f), -80.f);
    float d3 = fmaxf(fminf(v3 - mx, 0.f), -80.f);
    float e0 = __expf(d0), e1 = __expf(d1), e2 = __expf(d2), e3 = __expf(d3);
    red[tid] = e0 + e1 + e2 + e3;
    __syncthreads();
    for (int s = 128; s > 0; s >>= 1) { if (tid < s) red[tid] += red[tid + s]; __syncthreads(); }
    float inv = 1.f / red[0];
    pb[tid]       = __float2bfloat16(e0 * inv);
    pb[tid + 256] = __float2bfloat16(e1 * inv);
    pb[tid + 512] = __float2bfloat16(e2 * inv);
    pb[tid + 768] = __float2bfloat16(e3 * inv);
}

// ---------------------------------------------------------------------------
// K8: output MFMA. out[c][m] = gamma * sum_n Yv[c][n] * P[m][n] + x[c][m].
// P read at pitch 2048 (aliased in fp32 S rows).
// ---------------------------------------------------------------------------
__global__ __launch_bounds__(256) void k_out(
    const bf16* __restrict__ YV, const char* __restrict__ SX,
    const void* __restrict__ x, const void* __restrict__ gamma,
    const int* __restrict__ flag, void* __restrict__ out, int batch0)
{
    __shared__ __bf16 Als[128][40];
    __shared__ __bf16 Bls[128][40];
    int f32 = *flag;
    int z = blockIdx.z, c0 = blockIdx.y * 128, m0 = blockIdx.x * 128;
    const bf16* Yv = YV + (size_t)z * 524288;
    const bf16* Pb = (const bf16*)(SX + (size_t)z * 4194304);   // pitch 2048
    int tid = threadIdx.x, wave = tid >> 6, lane = tid & 63, quad = lane >> 4, l16 = lane & 15;
    int wc = (wave >> 1) * 64, wm = (wave & 1) * 64;

    f32x4 acc[4][4];
#pragma unroll
    for (int i = 0; i < 4; ++i)
#pragma unroll
        for (int j = 0; j < 4; ++j) acc[i][j] = (f32x4){0.f, 0.f, 0.f, 0.f};

    for (int k0 = 0; k0 < N_SP; k0 += 32) {
#pragma unroll
        for (int s = 0; s < 2; ++s) {
            int idx = tid + s * 256; int row = idx >> 2, ch = idx & 3;
            *reinterpret_cast<uint4*>(&Als[row][ch * 8]) =
                *reinterpret_cast<const uint4*>(&Yv[(size_t)(c0 + row) * N_SP + k0 + ch * 8]);
            *reinterpret_cast<uint4*>(&Bls[row][ch * 8]) =
                *reinterpret_cast<const uint4*>(&Pb[(size_t)(m0 + row) * 2048 + k0 + ch * 8]);
        }
        __syncthreads();
        bf16x8 a[4], b[4];
#pragma unroll
        for (int i = 0; i < 4; ++i)
            a[i] = *reinterpret_cast<const bf16x8*>(&Als[wc + i * 16 + l16][quad * 8]);
#pragma unroll
        for (int j = 0; j < 4; ++j)
            b[j] = *reinterpret_cast<const bf16x8*>(&Bls[wm + j * 16 + l16][quad * 8]);
#pragma unroll
        for (int i = 0; i < 4; ++i)
#pragma unroll
            for (int j = 0; j < 4; ++j)
                acc[i][j] = __builtin_amdgcn_mfma_f32_16x16x32_bf16(a[i], b[j], acc[i][j], 0, 0, 0);
        __syncthreads();
    }

    float g = ldmix(gamma, 0, f32);
    const size_t base = (size_t)(batch0 + z) * C_IN * N_SP;
#pragma unroll
    for (int i = 0; i < 4; ++i)
#pragma unroll
        for (int j = 0; j < 4; ++j)
#pragma unroll
            for (int r = 0; r < 4; ++r) {
                int c = c0 + wc + i * 16 + quad * 4 + r;
                int m = m0 + wm + j * 16 + l16;
                size_t o = base + (size_t)c * N_SP + m;
                float v = fmaf(g, acc[i][j][r], ldmix(x, o, f32));
                if (!(v == v)) v = 5555.0f + 1000.0f * f32;   // NaN sentinel
                stmix(out, o, v, f32);
            }
}

// Diagnostic: workspace too small even for GB=1.
__global__ void k_wsfail(float* __restrict__ out, int n)
{
    int i = blockIdx.x * 256 + threadIdx.x;
    if (i < n) out[i] = 7777.0f;
}

// ---------------------------------------------------------------------------
extern "C" void kernel_launch(void* const* d_in, const int* in_sizes, int n_in,
                              void* d_out, int out_size, void* d_ws, size_t ws_size,
                              hipStream_t stream)
{
    const void* x  = d_in[0];
    const void* Wq = d_in[1];
    const void* bq = d_in[2];
    const void* Wk = d_in[4];
    const void* bk = d_in[5];
    const void* Wv = d_in[7];
    const void* bv = d_in[8];
    const void* uq = d_in[3];
    const void* uk = d_in[6];
    const void* uv = d_in[9];
    const void* gm = d_in[10];

    // ws layout:
    //   flag @0, sig[3] @16, biasf[640] @256, Wb bf16[640][512] @4096,
    //   Wlo bf16[128][512] @659456 -> group region @790528:
    //     SX: GB x 4MB  (xT_hi 1MB | xT_lo 1MB | ...), later fp32 S overwrites
    //     QT: GB x 128KB, KT: GB x 128KB, YV: GB x 1MB
    const size_t HDR = 790528;
    const size_t per = 4194304 + 131072 + 131072 + 1048576;   // 5,505,024
    int GB = 0;
    for (int g = 8; g >= 1; g >>= 1)
        if (HDR + (size_t)g * per <= ws_size) { GB = g; break; }
    if (GB == 0) {
        k_wsfail<<<(out_size + 255) / 256, 256, 0, stream>>>((float*)d_out, out_size);
        return;
    }
    char* ws = (char*)d_ws;
    int*   flag  = (int*)ws;
    float* sig   = (float*)(ws + 16);
    float* biasf = (float*)(ws + 256);
    bf16*  Wb    = (bf16*)(ws + 4096);
    bf16*  Wlo   = (bf16*)(ws + 659456);
    char*  SX    = ws + HDR;
    bf16*  QT    = (bf16*)(SX + (size_t)GB * 4194304);
    bf16*  KT    = QT + (size_t)GB * 65536;
    bf16*  YV    = KT + (size_t)GB * 65536;

    k_detect<<<1, 256, 0, stream>>>((const unsigned short*)x, flag);
    k_spectral<<<3, 512, 0, stream>>>(Wq, uq, Wk, uk, Wv, uv, flag, sig);
    k_wscale<<<640, 256, 0, stream>>>(Wq, bq, Wk, bk, Wv, bv, sig, flag, Wb, Wlo, biasf);
    for (int b0 = 0; b0 < BATCH; b0 += GB) {
        k_xt     <<<dim3(16, 8, GB), 256, 0, stream>>>(x, flag, SX, b0);
        k_qkv_v  <<<dim3(8, 4, GB), 256, 0, stream>>>(Wb, biasf, SX, YV);
        k_qkv_qk <<<dim3(16, 2, GB), 256, 0, stream>>>(Wb, Wlo, biasf, SX, QT, KT);
        k_qk     <<<dim3(8, 8, GB), 256, 0, stream>>>(QT, KT, SX);
        k_softmax<<<GB * 1024, 256, 0, stream>>>(SX);
        k_out    <<<dim3(8, 4, GB), 256, 0, stream>>>(YV, SX, x, gm, flag, d_out, b0);
    }
}